// Round 1
// baseline (3973.806 us; speedup 1.0000x reference)
//
#include <hip/hip_runtime.h>
#include <math.h>

#define BB 8
#define S 256
#define CIN 3
#define W64 64
#define MODES 32
#define PP 34     // MODES + BW - 1
#define KPAD 36   // padded leading dim for Dt

__device__ __forceinline__ float gelu_f(float x){
    return 0.5f * x * (1.0f + erff(x * 0.7071067811865476f));
}

// Dt[h*36 + k] = DCT[k, h]  (orthonormal DCT-II), k < 34, zero-padded to 36
__global__ void k_init_dt(float* __restrict__ dt){
    int tid = blockIdx.x * 256 + threadIdx.x;
    if (tid >= S * KPAD) return;
    int h = tid / KPAD, k = tid % KPAD;
    double v = 0.0;
    if (k < PP) {
        v = sqrt(2.0 / (double)S) * cos(3.14159265358979323846 * (h + 0.5) * k / (double)S);
        if (k == 0) v *= 0.70710678118654752440;
    }
    dt[tid] = (float)v;
}

// x (B,S,S,3) -> h channels 0..2 (channels-last h: (B,S,S,64))
__global__ void k_copy_x(const float* __restrict__ x, float* __restrict__ h){
    int e = blockIdx.x * 256 + threadIdx.x;
    if (e >= BB * S * S * CIN) return;
    int px = e / CIN, c = e % CIN;
    h[(size_t)px * W64 + c] = x[e];
}

// tmp1[b][k][w][c] = sum_h Dt[h][k] * src[b][h][w][c]   (k < 34)
template<int C>
__global__ void k_fwd1(const float* __restrict__ src, float* __restrict__ tmp1,
                       const float* __restrict__ dt){
    int b = blockIdx.y;
    int idx = blockIdx.x * 256 + threadIdx.x;   // flat (w, c)
    if (idx >= S * C) return;
    float acc[PP];
    #pragma unroll
    for (int k = 0; k < PP; k++) acc[k] = 0.f;
    const float* sp = src + (size_t)b * S * S * C + idx;
    for (int hh = 0; hh < S; hh++){
        float v = sp[(size_t)hh * S * C];
        const float* dr = dt + hh * KPAD;
        #pragma unroll
        for (int k = 0; k < PP; k++) acc[k] = fmaf(dr[k], v, acc[k]);
    }
    float* op = tmp1 + (size_t)b * PP * S * C + idx;
    #pragma unroll
    for (int k = 0; k < PP; k++) op[(size_t)k * S * C] = acc[k];
}

// bp[b][k][l][c] = sum_w Dt[w][l] * tmp1[b][k][w][c]
template<int C>
__global__ void k_fwd2(const float* __restrict__ tmp1, float* __restrict__ bp,
                       const float* __restrict__ dt){
    int b = blockIdx.y;
    int idx = blockIdx.x * 256 + threadIdx.x;   // flat (k, c)
    if (idx >= PP * C) return;
    int k = idx / C, c = idx % C;
    float acc[PP];
    #pragma unroll
    for (int l = 0; l < PP; l++) acc[l] = 0.f;
    const float* sp = tmp1 + ((size_t)b * PP + k) * S * C + c;
    for (int w = 0; w < S; w++){
        float v = sp[(size_t)w * C];
        const float* dr = dt + w * KPAD;
        #pragma unroll
        for (int l = 0; l < PP; l++) acc[l] = fmaf(dr[l], v, acc[l]);
    }
    float* op = bp + ((size_t)b * PP + k) * PP * C + c;
    #pragma unroll
    for (int l = 0; l < PP; l++) op[(size_t)l * C] = acc[l];
}

// xp[i][kl][b] = bp[b][k+i_][l+j_][c],  i = c*9 + i_*3 + j_, kl = k*32 + l
template<int C, int CC>
__global__ void k_xp_gather(const float* __restrict__ bp, float* __restrict__ xp){
    __shared__ float lds[8 * 3 * PP * (CC + 1)];
    int k  = blockIdx.x;           // 0..31
    int c0 = blockIdx.y * CC;
    int t  = threadIdx.x;
    const int TOT = 8 * 3 * PP * CC;
    for (int e = t; e < TOT; e += 256){
        int b   = e / (3 * PP * CC);
        int r   = e % (3 * PP * CC);
        int row = r / (PP * CC);
        int r2  = r % (PP * CC);
        int l   = r2 / CC;
        int c   = r2 % CC;
        lds[((b * 3 + row) * PP + l) * (CC + 1) + c] =
            bp[(((size_t)b * PP + (k + row)) * PP + l) * C + c0 + c];
    }
    __syncthreads();
    int l = t >> 3;   // 0..31
    int b = t & 7;
    for (int c = 0; c < CC; c++){
        #pragma unroll
        for (int ij = 0; ij < 9; ij++){
            int i_ = ij / 3, j_ = ij % 3;
            int i  = (c0 + c) * 9 + ij;
            float v = lds[((b * 3 + i_) * PP + (l + j_)) * (CC + 1) + c];
            xp[((size_t)i * 1024 + k * 32 + l) * 8 + b] = v;
        }
    }
}

// part[ns][b][o][kl] = sum_{i in slice ns} xp[i][kl][b] * w[i][o][kl]
template<int ITOT, int O>
__global__ void k_om(const float* __restrict__ xp, const float* __restrict__ w,
                     float* __restrict__ part){
    int bx  = blockIdx.x;
    int klt = bx & 63;
    int ot  = (bx >> 6) & 3;
    int ns  = bx >> 8;              // 0..2
    const int ILEN = ITOT / 3;
    int t  = threadIdx.x;
    int kl = klt * 16 + (t & 15);
    int o  = ot * 16 + (t >> 4);
    if (o >= O) return;
    float a0=0,a1=0,a2=0,a3=0,a4=0,a5=0,a6=0,a7=0;
    const float* xpp = xp + ((size_t)(ns * ILEN) * 1024 + kl) * 8;
    const float* wp  = w + ((size_t)(ns * ILEN) * O + o) * 1024 + kl;
    #pragma unroll 4
    for (int i = 0; i < ILEN; i++){
        float4 xa = *(const float4*)(xpp + (size_t)i * 8192);
        float4 xb = *(const float4*)(xpp + (size_t)i * 8192 + 4);
        float wv  = wp[(size_t)i * O * 1024];
        a0 = fmaf(xa.x, wv, a0); a1 = fmaf(xa.y, wv, a1);
        a2 = fmaf(xa.z, wv, a2); a3 = fmaf(xa.w, wv, a3);
        a4 = fmaf(xb.x, wv, a4); a5 = fmaf(xb.y, wv, a5);
        a6 = fmaf(xb.z, wv, a6); a7 = fmaf(xb.w, wv, a7);
    }
    float* pp = part + (size_t)ns * 8 * 64 * 1024;
    pp[((size_t)0 * 64 + o) * 1024 + kl] = a0;
    pp[((size_t)1 * 64 + o) * 1024 + kl] = a1;
    pp[((size_t)2 * 64 + o) * 1024 + kl] = a2;
    pp[((size_t)3 * 64 + o) * 1024 + kl] = a3;
    pp[((size_t)4 * 64 + o) * 1024 + kl] = a4;
    pp[((size_t)5 * 64 + o) * 1024 + kl] = a5;
    pp[((size_t)6 * 64 + o) * 1024 + kl] = a6;
    pp[((size_t)7 * 64 + o) * 1024 + kl] = a7;
}

__global__ void k_om_reduce(const float* __restrict__ part, float* __restrict__ om){
    const int N = 8 * 64 * 1024;
    int e = blockIdx.x * 256 + threadIdx.x;
    if (e >= N) return;
    om[e] = part[e] + part[N + e] + part[2 * N + e];
}

// t2[b][k][w][o] = sum_l Dt[w][l] * om[b][o][k*32+l]
template<int O>
__global__ void k_inv1(const float* __restrict__ om, float* __restrict__ t2,
                       const float* __restrict__ dt){
    __shared__ float oms[32 * 65];
    int wc = blockIdx.x, k = blockIdx.y, b = blockIdx.z;
    int t = threadIdx.x;
    for (int e = t; e < 2048; e += 256){
        int o_ = e >> 5, l = e & 31;
        oms[l * 65 + o_] = om[((size_t)b * 64 + o_) * 1024 + k * 32 + l];
    }
    __syncthreads();
    int o  = t & 63;
    int wg = __builtin_amdgcn_readfirstlane(t >> 6);
    int wbase = wc * 32 + wg * 8;
    float acc[8];
    #pragma unroll
    for (int wj = 0; wj < 8; wj++) acc[wj] = 0.f;
    for (int l = 0; l < 32; l++){
        float ov = oms[l * 65 + o];
        #pragma unroll
        for (int wj = 0; wj < 8; wj++)
            acc[wj] = fmaf(dt[(wbase + wj) * KPAD + l], ov, acc[wj]);
    }
    if (o < O){
        #pragma unroll
        for (int wj = 0; wj < 8; wj++)
            t2[(((size_t)b * 32 + k) * S + wbase + wj) * 64 + o] = acc[wj];
    }
}

// h[b][hh][w][o] += gelu( conv1x1(h)[o] + pb[o] + sum_k Dt[hh][k]*t2[b][k][w][o] )
__global__ void k_fused(const float* __restrict__ t2, float* __restrict__ h,
                        const float* __restrict__ pw, const float* __restrict__ pb,
                        const float* __restrict__ dt){
    __shared__ float t2s[32 * 4 * 64];
    int wt = blockIdx.x, ht = blockIdx.y, b = blockIdx.z;
    int t = threadIdx.x;
    int o = t & 63;
    int wave = __builtin_amdgcn_readfirstlane(t >> 6);
    int w0 = wt * 4;
    int hh0 = ht * 32 + wave * 8;
    for (int e4 = t; e4 < 2048; e4 += 256){
        int k = e4 >> 6, r4 = e4 & 63;
        ((float4*)t2s)[e4] =
            *(const float4*)(t2 + ((size_t)b * 32 + k) * S * 64 + (size_t)w0 * 64 + r4 * 4);
    }
    __syncthreads();
    float pwr[64];
    const float4* pwp = (const float4*)(pw + (size_t)o * 64);
    #pragma unroll
    for (int q = 0; q < 16; q++){
        float4 v = pwp[q];
        pwr[4*q] = v.x; pwr[4*q+1] = v.y; pwr[4*q+2] = v.z; pwr[4*q+3] = v.w;
    }
    float acc[8][4];
    #pragma unroll
    for (int hj = 0; hj < 8; hj++){
        #pragma unroll
        for (int wj = 0; wj < 4; wj++){
            const float4* hp = (const float4*)(h + (((size_t)b * S + hh0 + hj) * S + w0 + wj) * 64);
            float s = 0.f;
            #pragma unroll
            for (int q = 0; q < 16; q++){
                float4 hv = hp[q];
                s = fmaf(hv.x, pwr[4*q],   s);
                s = fmaf(hv.y, pwr[4*q+1], s);
                s = fmaf(hv.z, pwr[4*q+2], s);
                s = fmaf(hv.w, pwr[4*q+3], s);
            }
            acc[hj][wj] = s;
        }
    }
    for (int k = 0; k < 32; k++){
        float tv0 = t2s[(k*4+0)*64 + o];
        float tv1 = t2s[(k*4+1)*64 + o];
        float tv2 = t2s[(k*4+2)*64 + o];
        float tv3 = t2s[(k*4+3)*64 + o];
        #pragma unroll
        for (int hj = 0; hj < 8; hj++){
            float d = dt[(hh0 + hj) * KPAD + k];
            acc[hj][0] = fmaf(d, tv0, acc[hj][0]);
            acc[hj][1] = fmaf(d, tv1, acc[hj][1]);
            acc[hj][2] = fmaf(d, tv2, acc[hj][2]);
            acc[hj][3] = fmaf(d, tv3, acc[hj][3]);
        }
    }
    float pbv = pb[o];
    #pragma unroll
    for (int hj = 0; hj < 8; hj++){
        #pragma unroll
        for (int wj = 0; wj < 4; wj++){
            size_t pix = ((size_t)b * S + hh0 + hj) * S + w0 + wj;
            float g = gelu_f(acc[hj][wj] + pbv);
            h[pix * 64 + o] += g;
        }
    }
}

// h[b][hh][w][3+o] = gelu( sum_k Dt[hh][k]*t2[b][k][w][o] ),  o < 61
__global__ void k_fused_b0(const float* __restrict__ t2, float* __restrict__ h,
                           const float* __restrict__ dt){
    __shared__ float t2s[32 * 4 * 64];
    int wt = blockIdx.x, ht = blockIdx.y, b = blockIdx.z;
    int t = threadIdx.x;
    int o = t & 63;
    int wave = __builtin_amdgcn_readfirstlane(t >> 6);
    int w0 = wt * 4;
    int hh0 = ht * 32 + wave * 8;
    for (int e4 = t; e4 < 2048; e4 += 256){
        int k = e4 >> 6, r4 = e4 & 63;
        ((float4*)t2s)[e4] =
            *(const float4*)(t2 + ((size_t)b * 32 + k) * S * 64 + (size_t)w0 * 64 + r4 * 4);
    }
    __syncthreads();
    float acc[8][4];
    #pragma unroll
    for (int hj = 0; hj < 8; hj++)
        #pragma unroll
        for (int wj = 0; wj < 4; wj++) acc[hj][wj] = 0.f;
    for (int k = 0; k < 32; k++){
        float tv0 = t2s[(k*4+0)*64 + o];
        float tv1 = t2s[(k*4+1)*64 + o];
        float tv2 = t2s[(k*4+2)*64 + o];
        float tv3 = t2s[(k*4+3)*64 + o];
        #pragma unroll
        for (int hj = 0; hj < 8; hj++){
            float d = dt[(hh0 + hj) * KPAD + k];
            acc[hj][0] = fmaf(d, tv0, acc[hj][0]);
            acc[hj][1] = fmaf(d, tv1, acc[hj][1]);
            acc[hj][2] = fmaf(d, tv2, acc[hj][2]);
            acc[hj][3] = fmaf(d, tv3, acc[hj][3]);
        }
    }
    if (o < 61){
        #pragma unroll
        for (int hj = 0; hj < 8; hj++){
            #pragma unroll
            for (int wj = 0; wj < 4; wj++){
                size_t pix = ((size_t)b * S + hh0 + hj) * S + w0 + wj;
                h[pix * 64 + 3 + o] = gelu_f(acc[hj][wj]);
            }
        }
    }
}

// out[b][hh][w] = gelu(h_px @ fc1 + b1) @ fc2 + b2
__global__ void k_mlp(const float* __restrict__ h, const float* __restrict__ fc1w,
                      const float* __restrict__ fc1b, const float* __restrict__ fc2w,
                      const float* __restrict__ fc2b, float* __restrict__ out){
    __shared__ float hs[256 * 64];
    int hh = blockIdx.x, b = blockIdx.y;
    int t = threadIdx.x;
    const float* hrow = h + ((size_t)b * S + hh) * S * 64;
    for (int e = t; e < 16384; e += 256){
        int w = e >> 6, i = e & 63;
        hs[w * 64 + (i ^ (w & 31))] = hrow[e];
    }
    __syncthreads();
    int w = t;
    float acc[128];
    #pragma unroll
    for (int j = 0; j < 128; j++) acc[j] = fc1b[j];
    for (int i = 0; i < 64; i++){
        float hv = hs[w * 64 + (i ^ (w & 31))];
        const float* f1 = fc1w + i * 128;
        #pragma unroll
        for (int j = 0; j < 128; j++) acc[j] = fmaf(hv, f1[j], acc[j]);
    }
    float y = fc2b[0];
    #pragma unroll
    for (int j = 0; j < 128; j++) y = fmaf(gelu_f(acc[j]), fc2w[j], y);
    out[((size_t)b * S + hh) * S + w] = y;
}

extern "C" void kernel_launch(void* const* d_in, const int* in_sizes, int n_in,
                              void* d_out, int out_size, void* d_ws, size_t ws_size,
                              hipStream_t stream) {
    const float* x    = (const float*)d_in[0];
    const float* wl   = (const float*)d_in[1];
    const float* wc[4] = {(const float*)d_in[2], (const float*)d_in[3],
                          (const float*)d_in[4], (const float*)d_in[5]};
    const float* pw[4] = {(const float*)d_in[6], (const float*)d_in[8],
                          (const float*)d_in[10], (const float*)d_in[12]};
    const float* pb[4] = {(const float*)d_in[7], (const float*)d_in[9],
                          (const float*)d_in[11], (const float*)d_in[13]};
    const float* fc1w = (const float*)d_in[14];
    const float* fc1b = (const float*)d_in[15];
    const float* fc2w = (const float*)d_in[16];
    const float* fc2b = (const float*)d_in[17];
    float* out = (float*)d_out;

    char* ws = (char*)d_ws;
    size_t off = 0;
    float* dt   = (float*)(ws + off); off += (size_t)S * KPAD * 4;              // 36,864
    float* h    = (float*)(ws + off); off += (size_t)BB * S * S * W64 * 4;      // 134,217,728
    float* tmp1 = (float*)(ws + off); off += (size_t)BB * PP * S * W64 * 4;     // 17,825,792
    float* bp   = (float*)(ws + off); off += (size_t)BB * PP * PP * W64 * 4;    // 2,367,488
    float* xp   = (float*)(ws + off); off += (size_t)576 * 1024 * 8 * 4;        // 18,874,368
    float* om   = (float*)(ws + off); off += (size_t)8 * 64 * 1024 * 4;         // 2,097,152
    float* part = (float*)(ws + off); off += (size_t)3 * 8 * 64 * 1024 * 4;     // 6,291,456
    float* t2   = (float*)(ws + off); off += (size_t)BB * 32 * S * W64 * 4;     // 16,777,216

    k_init_dt<<<36, 256, 0, stream>>>(dt);
    k_copy_x<<<(BB * S * S * CIN + 255) / 256, 256, 0, stream>>>(x, h);

    // ---- block 0: h[:, :, :, 3:] = gelu(pseudo_spectra(x, wl, 61)) ----
    k_fwd1<3><<<dim3(3, BB), 256, 0, stream>>>(x, tmp1, dt);
    k_fwd2<3><<<dim3(1, BB), 256, 0, stream>>>(tmp1, bp, dt);
    k_xp_gather<3, 3><<<dim3(32, 1), 256, 0, stream>>>(bp, xp);
    k_om<27, 61><<<768, 256, 0, stream>>>(xp, wl, part);
    k_om_reduce<<<2048, 256, 0, stream>>>(part, om);
    k_inv1<61><<<dim3(8, 32, BB), 256, 0, stream>>>(om, t2, dt);
    k_fused_b0<<<dim3(64, 8, BB), 256, 0, stream>>>(t2, h, dt);

    // ---- blocks 1..4 ----
    for (int blk = 0; blk < 4; blk++){
        k_fwd1<64><<<dim3(64, BB), 256, 0, stream>>>(h, tmp1, dt);
        k_fwd2<64><<<dim3((PP * 64 + 255) / 256, BB), 256, 0, stream>>>(tmp1, bp, dt);
        k_xp_gather<64, 16><<<dim3(32, 4), 256, 0, stream>>>(bp, xp);
        k_om<576, 64><<<768, 256, 0, stream>>>(xp, wc[blk], part);
        k_om_reduce<<<2048, 256, 0, stream>>>(part, om);
        k_inv1<64><<<dim3(8, 32, BB), 256, 0, stream>>>(om, t2, dt);
        k_fused<<<dim3(64, 8, BB), 256, 0, stream>>>(t2, h, pw[blk], pb[blk], dt);
    }

    // ---- final MLP (T_fwd(T_inv2(.)) is identity for the orthonormal DCT) ----
    k_mlp<<<dim3(S, BB), 256, 0, stream>>>(h, fc1w, fc1b, fc2w, fc2b, out);
}

// Round 2
// 2792.656 us; speedup vs baseline: 1.4229x; 1.4229x over previous
//
#include <hip/hip_runtime.h>
#include <math.h>

#define BB 8
#define S 256
#define CIN 3
#define W64 64
#define MODES 32
#define PP 34     // MODES + BW - 1
#define KPAD 36   // padded leading dim for Dt

__device__ __forceinline__ float gelu_f(float x){
    return 0.5f * x * (1.0f + erff(x * 0.7071067811865476f));
}

// Dt[h*36 + k] = DCT[k, h]  (orthonormal DCT-II), k < 34, zero-padded to 36
__global__ void k_init_dt(float* __restrict__ dt){
    int tid = blockIdx.x * 256 + threadIdx.x;
    if (tid >= S * KPAD) return;
    int h = tid / KPAD, k = tid % KPAD;
    double v = 0.0;
    if (k < PP) {
        v = sqrt(2.0 / (double)S) * cos(3.14159265358979323846 * (h + 0.5) * k / (double)S);
        if (k == 0) v *= 0.70710678118654752440;
    }
    dt[tid] = (float)v;
}

// x (B,S,S,3) -> h channels 0..2 (channels-last h: (B,S,S,64))
__global__ void k_copy_x(const float* __restrict__ x, float* __restrict__ h){
    int e = blockIdx.x * 256 + threadIdx.x;
    if (e >= BB * S * S * CIN) return;
    int px = e / CIN, c = e % CIN;
    h[(size_t)px * W64 + c] = x[e];
}

// tmp1[b][k][w][c] = sum_h Dt[h][k] * src[b][h][w][c]   (k < 34)
template<int C>
__global__ void k_fwd1(const float* __restrict__ src, float* __restrict__ tmp1,
                       const float* __restrict__ dt){
    int b = blockIdx.y;
    int idx = blockIdx.x * 256 + threadIdx.x;   // flat (w, c)
    if (idx >= S * C) return;
    float acc[PP];
    #pragma unroll
    for (int k = 0; k < PP; k++) acc[k] = 0.f;
    const float* sp = src + (size_t)b * S * S * C + idx;
    for (int hh = 0; hh < S; hh++){
        float v = sp[(size_t)hh * S * C];
        const float* dr = dt + hh * KPAD;
        #pragma unroll
        for (int k = 0; k < PP; k++) acc[k] = fmaf(dr[k], v, acc[k]);
    }
    float* op = tmp1 + (size_t)b * PP * S * C + idx;
    #pragma unroll
    for (int k = 0; k < PP; k++) op[(size_t)k * S * C] = acc[k];
}

// bp[b][k][l][c] = sum_w Dt[w][l] * tmp1[b][k][w][c]
template<int C>
__global__ void k_fwd2(const float* __restrict__ tmp1, float* __restrict__ bp,
                       const float* __restrict__ dt){
    int b = blockIdx.y;
    int idx = blockIdx.x * 256 + threadIdx.x;   // flat (k, c)
    if (idx >= PP * C) return;
    int k = idx / C, c = idx % C;
    float acc[PP];
    #pragma unroll
    for (int l = 0; l < PP; l++) acc[l] = 0.f;
    const float* sp = tmp1 + ((size_t)b * PP + k) * S * C + c;
    for (int w = 0; w < S; w++){
        float v = sp[(size_t)w * C];
        const float* dr = dt + w * KPAD;
        #pragma unroll
        for (int l = 0; l < PP; l++) acc[l] = fmaf(dr[l], v, acc[l]);
    }
    float* op = bp + ((size_t)b * PP + k) * PP * C + c;
    #pragma unroll
    for (int l = 0; l < PP; l++) op[(size_t)l * C] = acc[l];
}

// xp[i][kl][b] = bp[b][k+i_][l+j_][c],  i = c*9 + i_*3 + j_, kl = k*32 + l
template<int C, int CC>
__global__ void k_xp_gather(const float* __restrict__ bp, float* __restrict__ xp){
    __shared__ float lds[8 * 3 * PP * (CC + 1)];
    int k  = blockIdx.x;           // 0..31
    int c0 = blockIdx.y * CC;
    int t  = threadIdx.x;
    const int TOT = 8 * 3 * PP * CC;
    for (int e = t; e < TOT; e += 256){
        int b   = e / (3 * PP * CC);
        int r   = e % (3 * PP * CC);
        int row = r / (PP * CC);
        int r2  = r % (PP * CC);
        int l   = r2 / CC;
        int c   = r2 % CC;
        lds[((b * 3 + row) * PP + l) * (CC + 1) + c] =
            bp[(((size_t)b * PP + (k + row)) * PP + l) * C + c0 + c];
    }
    __syncthreads();
    int l = t >> 3;   // 0..31
    int b = t & 7;
    for (int c = 0; c < CC; c++){
        #pragma unroll
        for (int ij = 0; ij < 9; ij++){
            int i_ = ij / 3, j_ = ij % 3;
            int i  = (c0 + c) * 9 + ij;
            float v = lds[((b * 3 + i_) * PP + (l + j_)) * (CC + 1) + c];
            xp[((size_t)i * 1024 + k * 32 + l) * 8 + b] = v;
        }
    }
}

// part[ns][b][o][kl] = sum_{i in slice ns} xp[i][kl][b] * w[i][o][kl]
// tiling: 32 kl x 8 o per block so each half-wave reads 128B-contiguous weights
template<int ITOT, int O>
__global__ void k_om(const float* __restrict__ xp, const float* __restrict__ w,
                     float* __restrict__ part){
    int bx  = blockIdx.x;
    int klt = bx & 31;
    int ot  = (bx >> 5) & 7;
    int ns  = bx >> 8;              // 0..2
    const int ILEN = ITOT / 3;
    int t  = threadIdx.x;
    int kl = klt * 32 + (t & 31);
    int o  = ot * 8 + (t >> 5);
    if (o >= O) return;
    float a0=0,a1=0,a2=0,a3=0,a4=0,a5=0,a6=0,a7=0;
    const float* xpp = xp + ((size_t)(ns * ILEN) * 1024 + kl) * 8;
    const float* wp  = w + ((size_t)(ns * ILEN) * O + o) * 1024 + kl;
    #pragma unroll 4
    for (int i = 0; i < ILEN; i++){
        float4 xa = *(const float4*)(xpp + (size_t)i * 8192);
        float4 xb = *(const float4*)(xpp + (size_t)i * 8192 + 4);
        float wv  = wp[(size_t)i * O * 1024];
        a0 = fmaf(xa.x, wv, a0); a1 = fmaf(xa.y, wv, a1);
        a2 = fmaf(xa.z, wv, a2); a3 = fmaf(xa.w, wv, a3);
        a4 = fmaf(xb.x, wv, a4); a5 = fmaf(xb.y, wv, a5);
        a6 = fmaf(xb.z, wv, a6); a7 = fmaf(xb.w, wv, a7);
    }
    float* pp = part + (size_t)ns * 8 * 64 * 1024;
    pp[((size_t)0 * 64 + o) * 1024 + kl] = a0;
    pp[((size_t)1 * 64 + o) * 1024 + kl] = a1;
    pp[((size_t)2 * 64 + o) * 1024 + kl] = a2;
    pp[((size_t)3 * 64 + o) * 1024 + kl] = a3;
    pp[((size_t)4 * 64 + o) * 1024 + kl] = a4;
    pp[((size_t)5 * 64 + o) * 1024 + kl] = a5;
    pp[((size_t)6 * 64 + o) * 1024 + kl] = a6;
    pp[((size_t)7 * 64 + o) * 1024 + kl] = a7;
}

__global__ void k_om_reduce(const float* __restrict__ part, float* __restrict__ om){
    const int N = 8 * 64 * 1024;
    int e = blockIdx.x * 256 + threadIdx.x;
    if (e >= N) return;
    om[e] = part[e] + part[N + e] + part[2 * N + e];
}

// t2[b][k][w][o] = sum_l Dt[w][l] * om[b][o][k*32+l]
template<int O>
__global__ void k_inv1(const float* __restrict__ om, float* __restrict__ t2,
                       const float* __restrict__ dt){
    __shared__ float oms[32 * 65];
    int wc = blockIdx.x, k = blockIdx.y, b = blockIdx.z;
    int t = threadIdx.x;
    for (int e = t; e < 2048; e += 256){
        int o_ = e >> 5, l = e & 31;
        oms[l * 65 + o_] = om[((size_t)b * 64 + o_) * 1024 + k * 32 + l];
    }
    __syncthreads();
    int o  = t & 63;
    int wg = __builtin_amdgcn_readfirstlane(t >> 6);
    int wbase = wc * 32 + wg * 8;
    float acc[8];
    #pragma unroll
    for (int wj = 0; wj < 8; wj++) acc[wj] = 0.f;
    for (int l = 0; l < 32; l++){
        float ov = oms[l * 65 + o];
        #pragma unroll
        for (int wj = 0; wj < 8; wj++)
            acc[wj] = fmaf(dt[(wbase + wj) * KPAD + l], ov, acc[wj]);
    }
    if (o < O){
        #pragma unroll
        for (int wj = 0; wj < 8; wj++)
            t2[(((size_t)b * 32 + k) * S + wbase + wj) * 64 + o] = acc[wj];
    }
}

// h[b][hh][w][o] += gelu( conv1x1(h)[o] + pb[o] + sum_k Dt[hh][k]*t2[b][k][w][o] )
__global__ void k_fused(const float* __restrict__ t2, float* __restrict__ h,
                        const float* __restrict__ pw, const float* __restrict__ pb,
                        const float* __restrict__ dt){
    __shared__ float t2s[32 * 4 * 64];
    int wt = blockIdx.x, ht = blockIdx.y, b = blockIdx.z;
    int t = threadIdx.x;
    int o = t & 63;
    int wave = __builtin_amdgcn_readfirstlane(t >> 6);
    int w0 = wt * 4;
    int hh0 = ht * 32 + wave * 8;
    for (int e4 = t; e4 < 2048; e4 += 256){
        int k = e4 >> 6, r4 = e4 & 63;
        ((float4*)t2s)[e4] =
            *(const float4*)(t2 + ((size_t)b * 32 + k) * S * 64 + (size_t)w0 * 64 + r4 * 4);
    }
    __syncthreads();
    float pwr[64];
    const float4* pwp = (const float4*)(pw + (size_t)o * 64);
    #pragma unroll
    for (int q = 0; q < 16; q++){
        float4 v = pwp[q];
        pwr[4*q] = v.x; pwr[4*q+1] = v.y; pwr[4*q+2] = v.z; pwr[4*q+3] = v.w;
    }
    float acc[8][4];
    #pragma unroll
    for (int hj = 0; hj < 8; hj++){
        #pragma unroll
        for (int wj = 0; wj < 4; wj++){
            const float4* hp = (const float4*)(h + (((size_t)b * S + hh0 + hj) * S + w0 + wj) * 64);
            float s = 0.f;
            #pragma unroll
            for (int q = 0; q < 16; q++){
                float4 hv = hp[q];
                s = fmaf(hv.x, pwr[4*q],   s);
                s = fmaf(hv.y, pwr[4*q+1], s);
                s = fmaf(hv.z, pwr[4*q+2], s);
                s = fmaf(hv.w, pwr[4*q+3], s);
            }
            acc[hj][wj] = s;
        }
    }
    for (int k = 0; k < 32; k++){
        float tv0 = t2s[(k*4+0)*64 + o];
        float tv1 = t2s[(k*4+1)*64 + o];
        float tv2 = t2s[(k*4+2)*64 + o];
        float tv3 = t2s[(k*4+3)*64 + o];
        #pragma unroll
        for (int hj = 0; hj < 8; hj++){
            float d = dt[(hh0 + hj) * KPAD + k];
            acc[hj][0] = fmaf(d, tv0, acc[hj][0]);
            acc[hj][1] = fmaf(d, tv1, acc[hj][1]);
            acc[hj][2] = fmaf(d, tv2, acc[hj][2]);
            acc[hj][3] = fmaf(d, tv3, acc[hj][3]);
        }
    }
    float pbv = pb[o];
    #pragma unroll
    for (int hj = 0; hj < 8; hj++){
        #pragma unroll
        for (int wj = 0; wj < 4; wj++){
            size_t pix = ((size_t)b * S + hh0 + hj) * S + w0 + wj;
            float g = gelu_f(acc[hj][wj] + pbv);
            h[pix * 64 + o] += g;
        }
    }
}

// h[b][hh][w][3+o] = gelu( sum_k Dt[hh][k]*t2[b][k][w][o] ),  o < 61
__global__ void k_fused_b0(const float* __restrict__ t2, float* __restrict__ h,
                           const float* __restrict__ dt){
    __shared__ float t2s[32 * 4 * 64];
    int wt = blockIdx.x, ht = blockIdx.y, b = blockIdx.z;
    int t = threadIdx.x;
    int o = t & 63;
    int wave = __builtin_amdgcn_readfirstlane(t >> 6);
    int w0 = wt * 4;
    int hh0 = ht * 32 + wave * 8;
    for (int e4 = t; e4 < 2048; e4 += 256){
        int k = e4 >> 6, r4 = e4 & 63;
        ((float4*)t2s)[e4] =
            *(const float4*)(t2 + ((size_t)b * 32 + k) * S * 64 + (size_t)w0 * 64 + r4 * 4);
    }
    __syncthreads();
    float acc[8][4];
    #pragma unroll
    for (int hj = 0; hj < 8; hj++)
        #pragma unroll
        for (int wj = 0; wj < 4; wj++) acc[hj][wj] = 0.f;
    for (int k = 0; k < 32; k++){
        float tv0 = t2s[(k*4+0)*64 + o];
        float tv1 = t2s[(k*4+1)*64 + o];
        float tv2 = t2s[(k*4+2)*64 + o];
        float tv3 = t2s[(k*4+3)*64 + o];
        #pragma unroll
        for (int hj = 0; hj < 8; hj++){
            float d = dt[(hh0 + hj) * KPAD + k];
            acc[hj][0] = fmaf(d, tv0, acc[hj][0]);
            acc[hj][1] = fmaf(d, tv1, acc[hj][1]);
            acc[hj][2] = fmaf(d, tv2, acc[hj][2]);
            acc[hj][3] = fmaf(d, tv3, acc[hj][3]);
        }
    }
    if (o < 61){
        #pragma unroll
        for (int hj = 0; hj < 8; hj++){
            #pragma unroll
            for (int wj = 0; wj < 4; wj++){
                size_t pix = ((size_t)b * S + hh0 + hj) * S + w0 + wj;
                h[pix * 64 + 3 + o] = gelu_f(acc[hj][wj]);
            }
        }
    }
}

// out[px] = gelu(h_px @ fc1 + b1) @ fc2 + b2
// 64 pixels per block; thread = (pixel p, j-chunk q of 32 hidden units).
// acc[32] stays in VGPRs (the old acc[128] spilled to scratch: 1.2 GB HBM/dispatch).
__global__ void k_mlp(const float* __restrict__ h, const float* __restrict__ fc1w,
                      const float* __restrict__ fc1b, const float* __restrict__ fc2w,
                      const float* __restrict__ fc2b, float* __restrict__ out){
    __shared__ float hs[64 * 65];
    __shared__ float red[256];
    size_t base = (size_t)blockIdx.x * 64;   // first pixel of this block
    int t = threadIdx.x;
    const float* hrow = h + base * 64;
    for (int e = t; e < 4096; e += 256){
        int p = e >> 6, i = e & 63;
        hs[p * 65 + i] = hrow[e];
    }
    __syncthreads();
    int p = t & 63;
    int q = __builtin_amdgcn_readfirstlane(t >> 6);   // wave-uniform j-chunk
    float acc[32];
    const float* b1 = fc1b + q * 32;
    #pragma unroll
    for (int j = 0; j < 32; j++) acc[j] = b1[j];
    for (int i = 0; i < 64; i++){
        float hv = hs[p * 65 + i];
        const float* f1 = fc1w + i * 128 + q * 32;    // wave-uniform -> s_load
        #pragma unroll
        for (int j = 0; j < 32; j++) acc[j] = fmaf(hv, f1[j], acc[j]);
    }
    const float* f2 = fc2w + q * 32;
    float y = 0.f;
    #pragma unroll
    for (int j = 0; j < 32; j++) y = fmaf(gelu_f(acc[j]), f2[j], y);
    red[t] = y;
    __syncthreads();
    if (t < 64){
        out[base + t] = red[t] + red[64 + t] + red[128 + t] + red[192 + t] + fc2b[0];
    }
}

extern "C" void kernel_launch(void* const* d_in, const int* in_sizes, int n_in,
                              void* d_out, int out_size, void* d_ws, size_t ws_size,
                              hipStream_t stream) {
    const float* x    = (const float*)d_in[0];
    const float* wl   = (const float*)d_in[1];
    const float* wc[4] = {(const float*)d_in[2], (const float*)d_in[3],
                          (const float*)d_in[4], (const float*)d_in[5]};
    const float* pw[4] = {(const float*)d_in[6], (const float*)d_in[8],
                          (const float*)d_in[10], (const float*)d_in[12]};
    const float* pb[4] = {(const float*)d_in[7], (const float*)d_in[9],
                          (const float*)d_in[11], (const float*)d_in[13]};
    const float* fc1w = (const float*)d_in[14];
    const float* fc1b = (const float*)d_in[15];
    const float* fc2w = (const float*)d_in[16];
    const float* fc2b = (const float*)d_in[17];
    float* out = (float*)d_out;

    char* ws = (char*)d_ws;
    size_t off = 0;
    float* dt   = (float*)(ws + off); off += (size_t)S * KPAD * 4;              // 36,864
    float* h    = (float*)(ws + off); off += (size_t)BB * S * S * W64 * 4;      // 134,217,728
    float* tmp1 = (float*)(ws + off); off += (size_t)BB * PP * S * W64 * 4;     // 17,825,792
    float* bp   = (float*)(ws + off); off += (size_t)BB * PP * PP * W64 * 4;    // 2,367,488
    float* xp   = (float*)(ws + off); off += (size_t)576 * 1024 * 8 * 4;        // 18,874,368
    float* om   = (float*)(ws + off); off += (size_t)8 * 64 * 1024 * 4;         // 2,097,152
    float* part = (float*)(ws + off); off += (size_t)3 * 8 * 64 * 1024 * 4;     // 6,291,456
    float* t2   = (float*)(ws + off); off += (size_t)BB * 32 * S * W64 * 4;     // 16,777,216

    k_init_dt<<<36, 256, 0, stream>>>(dt);
    k_copy_x<<<(BB * S * S * CIN + 255) / 256, 256, 0, stream>>>(x, h);

    // ---- block 0: h[:, :, :, 3:] = gelu(pseudo_spectra(x, wl, 61)) ----
    k_fwd1<3><<<dim3(3, BB), 256, 0, stream>>>(x, tmp1, dt);
    k_fwd2<3><<<dim3(1, BB), 256, 0, stream>>>(tmp1, bp, dt);
    k_xp_gather<3, 3><<<dim3(32, 1), 256, 0, stream>>>(bp, xp);
    k_om<27, 61><<<768, 256, 0, stream>>>(xp, wl, part);
    k_om_reduce<<<2048, 256, 0, stream>>>(part, om);
    k_inv1<61><<<dim3(8, 32, BB), 256, 0, stream>>>(om, t2, dt);
    k_fused_b0<<<dim3(64, 8, BB), 256, 0, stream>>>(t2, h, dt);

    // ---- blocks 1..4 ----
    for (int blk = 0; blk < 4; blk++){
        k_fwd1<64><<<dim3(64, BB), 256, 0, stream>>>(h, tmp1, dt);
        k_fwd2<64><<<dim3((PP * 64 + 255) / 256, BB), 256, 0, stream>>>(tmp1, bp, dt);
        k_xp_gather<64, 16><<<dim3(32, 4), 256, 0, stream>>>(bp, xp);
        k_om<576, 64><<<768, 256, 0, stream>>>(xp, wc[blk], part);
        k_om_reduce<<<2048, 256, 0, stream>>>(part, om);
        k_inv1<64><<<dim3(8, 32, BB), 256, 0, stream>>>(om, t2, dt);
        k_fused<<<dim3(64, 8, BB), 256, 0, stream>>>(t2, h, pw[blk], pb[blk], dt);
    }

    // ---- final MLP (T_fwd(T_inv2(.)) is identity for the orthonormal DCT) ----
    k_mlp<<<dim3(BB * S * S / 64), 256, 0, stream>>>(h, fc1w, fc1b, fc2w, fc2b, out);
}

// Round 3
// 2777.604 us; speedup vs baseline: 1.4307x; 1.0054x over previous
//
#include <hip/hip_runtime.h>
#include <math.h>

#define BB 8
#define S 256
#define CIN 3
#define W64 64
#define MODES 32
#define PP 34     // MODES + BW - 1
#define KPAD 36   // padded leading dim for Dt

__device__ __forceinline__ float gelu_f(float x){
    return 0.5f * x * (1.0f + erff(x * 0.7071067811865476f));
}

// Dt[h*36 + k] = DCT[k, h]  (orthonormal DCT-II), k < 34, zero-padded to 36
__global__ void k_init_dt(float* __restrict__ dt){
    int tid = blockIdx.x * 256 + threadIdx.x;
    if (tid >= S * KPAD) return;
    int h = tid / KPAD, k = tid % KPAD;
    double v = 0.0;
    if (k < PP) {
        v = sqrt(2.0 / (double)S) * cos(3.14159265358979323846 * (h + 0.5) * k / (double)S);
        if (k == 0) v *= 0.70710678118654752440;
    }
    dt[tid] = (float)v;
}

// x (B,S,S,3) -> h channels 0..2 (channels-last h: (B,S,S,64))
__global__ void k_copy_x(const float* __restrict__ x, float* __restrict__ h){
    int e = blockIdx.x * 256 + threadIdx.x;
    if (e >= BB * S * S * CIN) return;
    int px = e / CIN, c = e % CIN;
    h[(size_t)px * W64 + c] = x[e];
}

// tmp1[b][k][w][c] = sum_h Dt[h][k] * src[b][h][w][c]   (k < 34)
template<int C>
__global__ void k_fwd1(const float* __restrict__ src, float* __restrict__ tmp1,
                       const float* __restrict__ dt){
    int b = blockIdx.y;
    int idx = blockIdx.x * 256 + threadIdx.x;   // flat (w, c)
    if (idx >= S * C) return;
    float acc[PP];
    #pragma unroll
    for (int k = 0; k < PP; k++) acc[k] = 0.f;
    const float* sp = src + (size_t)b * S * S * C + idx;
    for (int hh = 0; hh < S; hh++){
        float v = sp[(size_t)hh * S * C];
        const float* dr = dt + hh * KPAD;
        #pragma unroll
        for (int k = 0; k < PP; k++) acc[k] = fmaf(dr[k], v, acc[k]);
    }
    float* op = tmp1 + (size_t)b * PP * S * C + idx;
    #pragma unroll
    for (int k = 0; k < PP; k++) op[(size_t)k * S * C] = acc[k];
}

// bp[b][k][l][c] = sum_w Dt[w][l] * tmp1[b][k][w][c]
template<int C>
__global__ void k_fwd2(const float* __restrict__ tmp1, float* __restrict__ bp,
                       const float* __restrict__ dt){
    int b = blockIdx.y;
    int idx = blockIdx.x * 256 + threadIdx.x;   // flat (k, c)
    if (idx >= PP * C) return;
    int k = idx / C, c = idx % C;
    float acc[PP];
    #pragma unroll
    for (int l = 0; l < PP; l++) acc[l] = 0.f;
    const float* sp = tmp1 + ((size_t)b * PP + k) * S * C + c;
    for (int w = 0; w < S; w++){
        float v = sp[(size_t)w * C];
        const float* dr = dt + w * KPAD;
        #pragma unroll
        for (int l = 0; l < PP; l++) acc[l] = fmaf(dr[l], v, acc[l]);
    }
    float* op = bp + ((size_t)b * PP + k) * PP * C + c;
    #pragma unroll
    for (int l = 0; l < PP; l++) op[(size_t)l * C] = acc[l];
}

// xp[i][kl][b] = bp[b][k+i_][l+j_][c],  i = c*9 + i_*3 + j_, kl = k*32 + l
template<int C, int CC>
__global__ void k_xp_gather(const float* __restrict__ bp, float* __restrict__ xp){
    __shared__ float lds[8 * 3 * PP * (CC + 1)];
    int k  = blockIdx.x;           // 0..31
    int c0 = blockIdx.y * CC;
    int t  = threadIdx.x;
    const int TOT = 8 * 3 * PP * CC;
    for (int e = t; e < TOT; e += 256){
        int b   = e / (3 * PP * CC);
        int r   = e % (3 * PP * CC);
        int row = r / (PP * CC);
        int r2  = r % (PP * CC);
        int l   = r2 / CC;
        int c   = r2 % CC;
        lds[((b * 3 + row) * PP + l) * (CC + 1) + c] =
            bp[(((size_t)b * PP + (k + row)) * PP + l) * C + c0 + c];
    }
    __syncthreads();
    int l = t >> 3;   // 0..31
    int b = t & 7;
    for (int c = 0; c < CC; c++){
        #pragma unroll
        for (int ij = 0; ij < 9; ij++){
            int i_ = ij / 3, j_ = ij % 3;
            int i  = (c0 + c) * 9 + ij;
            float v = lds[((b * 3 + i_) * PP + (l + j_)) * (CC + 1) + c];
            xp[((size_t)i * 1024 + k * 32 + l) * 8 + b] = v;
        }
    }
}

// part[ns][b][o][kl] = sum_{i in slice ns} xp[i][kl][b] * w[i][o][kl]
// tiling: 32 kl x 8 o per block so each half-wave reads 128B-contiguous weights
template<int ITOT, int O>
__global__ void k_om(const float* __restrict__ xp, const float* __restrict__ w,
                     float* __restrict__ part){
    int bx  = blockIdx.x;
    int klt = bx & 31;
    int ot  = (bx >> 5) & 7;
    int ns  = bx >> 8;              // 0..2
    const int ILEN = ITOT / 3;
    int t  = threadIdx.x;
    int kl = klt * 32 + (t & 31);
    int o  = ot * 8 + (t >> 5);
    if (o >= O) return;
    float a0=0,a1=0,a2=0,a3=0,a4=0,a5=0,a6=0,a7=0;
    const float* xpp = xp + ((size_t)(ns * ILEN) * 1024 + kl) * 8;
    const float* wp  = w + ((size_t)(ns * ILEN) * O + o) * 1024 + kl;
    #pragma unroll 4
    for (int i = 0; i < ILEN; i++){
        float4 xa = *(const float4*)(xpp + (size_t)i * 8192);
        float4 xb = *(const float4*)(xpp + (size_t)i * 8192 + 4);
        float wv  = wp[(size_t)i * O * 1024];
        a0 = fmaf(xa.x, wv, a0); a1 = fmaf(xa.y, wv, a1);
        a2 = fmaf(xa.z, wv, a2); a3 = fmaf(xa.w, wv, a3);
        a4 = fmaf(xb.x, wv, a4); a5 = fmaf(xb.y, wv, a5);
        a6 = fmaf(xb.z, wv, a6); a7 = fmaf(xb.w, wv, a7);
    }
    float* pp = part + (size_t)ns * 8 * 64 * 1024;
    pp[((size_t)0 * 64 + o) * 1024 + kl] = a0;
    pp[((size_t)1 * 64 + o) * 1024 + kl] = a1;
    pp[((size_t)2 * 64 + o) * 1024 + kl] = a2;
    pp[((size_t)3 * 64 + o) * 1024 + kl] = a3;
    pp[((size_t)4 * 64 + o) * 1024 + kl] = a4;
    pp[((size_t)5 * 64 + o) * 1024 + kl] = a5;
    pp[((size_t)6 * 64 + o) * 1024 + kl] = a6;
    pp[((size_t)7 * 64 + o) * 1024 + kl] = a7;
}

__global__ void k_om_reduce(const float* __restrict__ part, float* __restrict__ om){
    const int N = 8 * 64 * 1024;
    int e = blockIdx.x * 256 + threadIdx.x;
    if (e >= N) return;
    om[e] = part[e] + part[N + e] + part[2 * N + e];
}

// t2[b][k][w][o] = sum_l Dt[w][l] * om[b][o][k*32+l]
template<int O>
__global__ void k_inv1(const float* __restrict__ om, float* __restrict__ t2,
                       const float* __restrict__ dt){
    __shared__ float oms[32 * 65];
    int wc = blockIdx.x, k = blockIdx.y, b = blockIdx.z;
    int t = threadIdx.x;
    for (int e = t; e < 2048; e += 256){
        int o_ = e >> 5, l = e & 31;
        oms[l * 65 + o_] = om[((size_t)b * 64 + o_) * 1024 + k * 32 + l];
    }
    __syncthreads();
    int o  = t & 63;
    int wg = __builtin_amdgcn_readfirstlane(t >> 6);
    int wbase = wc * 32 + wg * 8;
    float acc[8];
    #pragma unroll
    for (int wj = 0; wj < 8; wj++) acc[wj] = 0.f;
    for (int l = 0; l < 32; l++){
        float ov = oms[l * 65 + o];
        #pragma unroll
        for (int wj = 0; wj < 8; wj++)
            acc[wj] = fmaf(dt[(wbase + wj) * KPAD + l], ov, acc[wj]);
    }
    if (o < O){
        #pragma unroll
        for (int wj = 0; wj < 8; wj++)
            t2[(((size_t)b * 32 + k) * S + wbase + wj) * 64 + o] = acc[wj];
    }
}

// CONV:  h[b][hh][w][o] += gelu( conv1x1(h)[o] + pb[o] + sum_k Dt[hh][k]*t2[b][k][w][o] )
// !CONV: h[b][hh][w][3+o] = gelu( sum_k Dt[hh][k]*t2[b][k][w][o] )   (o < 61)
// lane = o; thread covers 8 hh x 4 w pixels. pw staged transposed in LDS
// (one vector ds_read per i, reused across 32 px). h conv-input read via
// wave-uniform scalar loads (b,hh0,hj,w0,i all SGPR-provable).
template<bool CONV>
__global__ void k_fused(const float* __restrict__ t2, float* __restrict__ h,
                        const float* __restrict__ pw, const float* __restrict__ pb,
                        const float* __restrict__ dt){
    __shared__ float t2s[32 * 4 * 64];   // 32 KB
    __shared__ float pws[64 * 65];       // 16.6 KB, pws[i][o] = pw[o][i]
    int ht = blockIdx.x, wt = blockIdx.y, b = blockIdx.z;
    int t = threadIdx.x;
    int o = t & 63;
    int wave = __builtin_amdgcn_readfirstlane(t >> 6);
    int w0 = wt * 4;
    int hh0 = ht * 32 + wave * 8;
    for (int e4 = t; e4 < 2048; e4 += 256){
        int k = e4 >> 6, r4 = e4 & 63;
        ((float4*)t2s)[e4] =
            *(const float4*)(t2 + ((size_t)b * 32 + k) * S * 64 + (size_t)w0 * 64 + r4 * 4);
    }
    if (CONV){
        for (int e = t; e < 4096; e += 256){
            int oo = e >> 6, i = e & 63;
            pws[i * 65 + oo] = pw[e];
        }
    }
    __syncthreads();

    float acc[8][4];
    #pragma unroll
    for (int hj = 0; hj < 8; hj++)
        #pragma unroll
        for (int wj = 0; wj < 4; wj++) acc[hj][wj] = 0.f;

    if (CONV){
        const float* hrow0 = h + (((size_t)b * S + hh0) * S + w0) * 64;
        #pragma unroll 4
        for (int i = 0; i < 64; i++){
            float wv = pws[i * 65 + o];
            #pragma unroll
            for (int hj = 0; hj < 8; hj++){
                const float* hrow = hrow0 + (size_t)hj * S * 64;   // wave-uniform
                acc[hj][0] = fmaf(hrow[0 * 64 + i], wv, acc[hj][0]);
                acc[hj][1] = fmaf(hrow[1 * 64 + i], wv, acc[hj][1]);
                acc[hj][2] = fmaf(hrow[2 * 64 + i], wv, acc[hj][2]);
                acc[hj][3] = fmaf(hrow[3 * 64 + i], wv, acc[hj][3]);
            }
        }
    }

    for (int k = 0; k < 32; k++){
        float tv0 = t2s[(k*4+0)*64 + o];
        float tv1 = t2s[(k*4+1)*64 + o];
        float tv2 = t2s[(k*4+2)*64 + o];
        float tv3 = t2s[(k*4+3)*64 + o];
        #pragma unroll
        for (int hj = 0; hj < 8; hj++){
            float d = dt[(hh0 + hj) * KPAD + k];   // wave-uniform -> s_load
            acc[hj][0] = fmaf(d, tv0, acc[hj][0]);
            acc[hj][1] = fmaf(d, tv1, acc[hj][1]);
            acc[hj][2] = fmaf(d, tv2, acc[hj][2]);
            acc[hj][3] = fmaf(d, tv3, acc[hj][3]);
        }
    }

    if (CONV){
        float pbv = pb[o];
        #pragma unroll
        for (int hj = 0; hj < 8; hj++){
            #pragma unroll
            for (int wj = 0; wj < 4; wj++){
                size_t pix = ((size_t)b * S + hh0 + hj) * S + w0 + wj;
                float g = gelu_f(acc[hj][wj] + pbv);
                h[pix * 64 + o] += g;
            }
        }
    } else {
        if (o < 61){
            #pragma unroll
            for (int hj = 0; hj < 8; hj++){
                #pragma unroll
                for (int wj = 0; wj < 4; wj++){
                    size_t pix = ((size_t)b * S + hh0 + hj) * S + w0 + wj;
                    h[pix * 64 + 3 + o] = gelu_f(acc[hj][wj]);
                }
            }
        }
    }
}

// out[px] = gelu(h_px @ fc1 + b1) @ fc2 + b2
__global__ void k_mlp(const float* __restrict__ h, const float* __restrict__ fc1w,
                      const float* __restrict__ fc1b, const float* __restrict__ fc2w,
                      const float* __restrict__ fc2b, float* __restrict__ out){
    __shared__ float hs[64 * 65];
    __shared__ float red[256];
    size_t base = (size_t)blockIdx.x * 64;   // first pixel of this block
    int t = threadIdx.x;
    const float* hrow = h + base * 64;
    for (int e = t; e < 4096; e += 256){
        int p = e >> 6, i = e & 63;
        hs[p * 65 + i] = hrow[e];
    }
    __syncthreads();
    int p = t & 63;
    int q = __builtin_amdgcn_readfirstlane(t >> 6);   // wave-uniform j-chunk
    float acc[32];
    const float* b1 = fc1b + q * 32;
    #pragma unroll
    for (int j = 0; j < 32; j++) acc[j] = b1[j];
    for (int i = 0; i < 64; i++){
        float hv = hs[p * 65 + i];
        const float* f1 = fc1w + i * 128 + q * 32;    // wave-uniform -> s_load
        #pragma unroll
        for (int j = 0; j < 32; j++) acc[j] = fmaf(hv, f1[j], acc[j]);
    }
    const float* f2 = fc2w + q * 32;
    float y = 0.f;
    #pragma unroll
    for (int j = 0; j < 32; j++) y = fmaf(gelu_f(acc[j]), f2[j], y);
    red[t] = y;
    __syncthreads();
    if (t < 64){
        out[base + t] = red[t] + red[64 + t] + red[128 + t] + red[192 + t] + fc2b[0];
    }
}

extern "C" void kernel_launch(void* const* d_in, const int* in_sizes, int n_in,
                              void* d_out, int out_size, void* d_ws, size_t ws_size,
                              hipStream_t stream) {
    const float* x    = (const float*)d_in[0];
    const float* wl   = (const float*)d_in[1];
    const float* wc[4] = {(const float*)d_in[2], (const float*)d_in[3],
                          (const float*)d_in[4], (const float*)d_in[5]};
    const float* pw[4] = {(const float*)d_in[6], (const float*)d_in[8],
                          (const float*)d_in[10], (const float*)d_in[12]};
    const float* pb[4] = {(const float*)d_in[7], (const float*)d_in[9],
                          (const float*)d_in[11], (const float*)d_in[13]};
    const float* fc1w = (const float*)d_in[14];
    const float* fc1b = (const float*)d_in[15];
    const float* fc2w = (const float*)d_in[16];
    const float* fc2b = (const float*)d_in[17];
    float* out = (float*)d_out;

    char* ws = (char*)d_ws;
    size_t off = 0;
    float* dt   = (float*)(ws + off); off += (size_t)S * KPAD * 4;              // 36,864
    float* h    = (float*)(ws + off); off += (size_t)BB * S * S * W64 * 4;      // 134,217,728
    float* tmp1 = (float*)(ws + off); off += (size_t)BB * PP * S * W64 * 4;     // 17,825,792
    float* bp   = (float*)(ws + off); off += (size_t)BB * PP * PP * W64 * 4;    // 2,367,488
    float* xp   = (float*)(ws + off); off += (size_t)576 * 1024 * 8 * 4;        // 18,874,368
    float* om   = (float*)(ws + off); off += (size_t)8 * 64 * 1024 * 4;         // 2,097,152
    float* part = (float*)(ws + off); off += (size_t)3 * 8 * 64 * 1024 * 4;     // 6,291,456
    float* t2   = (float*)(ws + off); off += (size_t)BB * 32 * S * W64 * 4;     // 16,777,216

    k_init_dt<<<36, 256, 0, stream>>>(dt);
    k_copy_x<<<(BB * S * S * CIN + 255) / 256, 256, 0, stream>>>(x, h);

    // ---- block 0: h[:, :, :, 3:] = gelu(pseudo_spectra(x, wl, 61)) ----
    k_fwd1<3><<<dim3(3, BB), 256, 0, stream>>>(x, tmp1, dt);
    k_fwd2<3><<<dim3(1, BB), 256, 0, stream>>>(tmp1, bp, dt);
    k_xp_gather<3, 3><<<dim3(32, 1), 256, 0, stream>>>(bp, xp);
    k_om<27, 61><<<768, 256, 0, stream>>>(xp, wl, part);
    k_om_reduce<<<2048, 256, 0, stream>>>(part, om);
    k_inv1<61><<<dim3(8, 32, BB), 256, 0, stream>>>(om, t2, dt);
    k_fused<false><<<dim3(8, 64, BB), 256, 0, stream>>>(t2, h, nullptr, nullptr, dt);

    // ---- blocks 1..4 ----
    for (int blk = 0; blk < 4; blk++){
        k_fwd1<64><<<dim3(64, BB), 256, 0, stream>>>(h, tmp1, dt);
        k_fwd2<64><<<dim3((PP * 64 + 255) / 256, BB), 256, 0, stream>>>(tmp1, bp, dt);
        k_xp_gather<64, 16><<<dim3(32, 4), 256, 0, stream>>>(bp, xp);
        k_om<576, 64><<<768, 256, 0, stream>>>(xp, wc[blk], part);
        k_om_reduce<<<2048, 256, 0, stream>>>(part, om);
        k_inv1<64><<<dim3(8, 32, BB), 256, 0, stream>>>(om, t2, dt);
        k_fused<true><<<dim3(8, 64, BB), 256, 0, stream>>>(t2, h, pw[blk], pb[blk], dt);
    }

    // ---- final MLP (T_fwd(T_inv2(.)) is identity for the orthonormal DCT) ----
    k_mlp<<<dim3(BB * S * S / 64), 256, 0, stream>>>(h, fc1w, fc1b, fc2w, fc2b, out);
}

// Round 4
// 1849.149 us; speedup vs baseline: 2.1490x; 1.5021x over previous
//
#include <hip/hip_runtime.h>
#include <math.h>

#define BB 8
#define S 256
#define CIN 3
#define W64 64
#define MODES 32
#define PP 34     // MODES + BW - 1
#define KPAD 36   // padded leading dim for Dt

__device__ __forceinline__ float gelu_f(float x){
    return 0.5f * x * (1.0f + erff(x * 0.7071067811865476f));
}

// Dt[h*36 + k] = DCT[k, h]  (orthonormal DCT-II), k < 34, zero-padded to 36
__global__ void k_init_dt(float* __restrict__ dt){
    int tid = blockIdx.x * 256 + threadIdx.x;
    if (tid >= S * KPAD) return;
    int h = tid / KPAD, k = tid % KPAD;
    double v = 0.0;
    if (k < PP) {
        v = sqrt(2.0 / (double)S) * cos(3.14159265358979323846 * (h + 0.5) * k / (double)S);
        if (k == 0) v *= 0.70710678118654752440;
    }
    dt[tid] = (float)v;
}

// x (B,S,S,3) -> h channels 0..2 (channels-last h: (B,S,S,64))
__global__ void k_copy_x(const float* __restrict__ x, float* __restrict__ h){
    int e = blockIdx.x * 256 + threadIdx.x;
    if (e >= BB * S * S * CIN) return;
    int px = e / CIN, c = e % CIN;
    h[(size_t)px * W64 + c] = x[e];
}

// tmp1[b][k][w][c] = sum_h Dt[h][k] * src[b][h][w][c]   (k < 34)
template<int C>
__global__ void k_fwd1(const float* __restrict__ src, float* __restrict__ tmp1,
                       const float* __restrict__ dt){
    int b = blockIdx.y;
    int idx = blockIdx.x * 256 + threadIdx.x;   // flat (w, c)
    if (idx >= S * C) return;
    float acc[PP];
    #pragma unroll
    for (int k = 0; k < PP; k++) acc[k] = 0.f;
    const float* sp = src + (size_t)b * S * S * C + idx;
    for (int hh = 0; hh < S; hh++){
        float v = sp[(size_t)hh * S * C];
        const float* dr = dt + hh * KPAD;
        #pragma unroll
        for (int k = 0; k < PP; k++) acc[k] = fmaf(dr[k], v, acc[k]);
    }
    float* op = tmp1 + (size_t)b * PP * S * C + idx;
    #pragma unroll
    for (int k = 0; k < PP; k++) op[(size_t)k * S * C] = acc[k];
}

// bp[b][k][l][c] = sum_w Dt[w][l] * tmp1[b][k][w][c]
template<int C>
__global__ void k_fwd2(const float* __restrict__ tmp1, float* __restrict__ bp,
                       const float* __restrict__ dt){
    int b = blockIdx.y;
    int idx = blockIdx.x * 256 + threadIdx.x;   // flat (k, c)
    if (idx >= PP * C) return;
    int k = idx / C, c = idx % C;
    float acc[PP];
    #pragma unroll
    for (int l = 0; l < PP; l++) acc[l] = 0.f;
    const float* sp = tmp1 + ((size_t)b * PP + k) * S * C + c;
    for (int w = 0; w < S; w++){
        float v = sp[(size_t)w * C];
        const float* dr = dt + w * KPAD;
        #pragma unroll
        for (int l = 0; l < PP; l++) acc[l] = fmaf(dr[l], v, acc[l]);
    }
    float* op = bp + ((size_t)b * PP + k) * PP * C + c;
    #pragma unroll
    for (int l = 0; l < PP; l++) op[(size_t)l * C] = acc[l];
}

// xp[i][kl][b] = bp[b][k+i_][l+j_][c],  i = c*9 + i_*3 + j_, kl = k*32 + l
template<int C, int CC>
__global__ void k_xp_gather(const float* __restrict__ bp, float* __restrict__ xp){
    __shared__ float lds[8 * 3 * PP * (CC + 1)];
    int k  = blockIdx.x;           // 0..31
    int c0 = blockIdx.y * CC;
    int t  = threadIdx.x;
    const int TOT = 8 * 3 * PP * CC;
    for (int e = t; e < TOT; e += 256){
        int b   = e / (3 * PP * CC);
        int r   = e % (3 * PP * CC);
        int row = r / (PP * CC);
        int r2  = r % (PP * CC);
        int l   = r2 / CC;
        int c   = r2 % CC;
        lds[((b * 3 + row) * PP + l) * (CC + 1) + c] =
            bp[(((size_t)b * PP + (k + row)) * PP + l) * C + c0 + c];
    }
    __syncthreads();
    int l = t >> 3;   // 0..31
    int b = t & 7;
    for (int c = 0; c < CC; c++){
        #pragma unroll
        for (int ij = 0; ij < 9; ij++){
            int i_ = ij / 3, j_ = ij % 3;
            int i  = (c0 + c) * 9 + ij;
            float v = lds[((b * 3 + i_) * PP + (l + j_)) * (CC + 1) + c];
            xp[((size_t)i * 1024 + k * 32 + l) * 8 + b] = v;
        }
    }
}

// part[ns][b][o][kl] = sum_{i in slice ns} xp[i][kl][b] * w[i][o][kl]
// tiling: 32 kl x 8 o per block so each half-wave reads 128B-contiguous weights
template<int ITOT, int O>
__global__ void k_om(const float* __restrict__ xp, const float* __restrict__ w,
                     float* __restrict__ part){
    int bx  = blockIdx.x;
    int klt = bx & 31;
    int ot  = (bx >> 5) & 7;
    int ns  = bx >> 8;              // 0..2
    const int ILEN = ITOT / 3;
    int t  = threadIdx.x;
    int kl = klt * 32 + (t & 31);
    int o  = ot * 8 + (t >> 5);
    if (o >= O) return;
    float a0=0,a1=0,a2=0,a3=0,a4=0,a5=0,a6=0,a7=0;
    const float* xpp = xp + ((size_t)(ns * ILEN) * 1024 + kl) * 8;
    const float* wp  = w + ((size_t)(ns * ILEN) * O + o) * 1024 + kl;
    #pragma unroll 4
    for (int i = 0; i < ILEN; i++){
        float4 xa = *(const float4*)(xpp + (size_t)i * 8192);
        float4 xb = *(const float4*)(xpp + (size_t)i * 8192 + 4);
        float wv  = wp[(size_t)i * O * 1024];
        a0 = fmaf(xa.x, wv, a0); a1 = fmaf(xa.y, wv, a1);
        a2 = fmaf(xa.z, wv, a2); a3 = fmaf(xa.w, wv, a3);
        a4 = fmaf(xb.x, wv, a4); a5 = fmaf(xb.y, wv, a5);
        a6 = fmaf(xb.z, wv, a6); a7 = fmaf(xb.w, wv, a7);
    }
    float* pp = part + (size_t)ns * 8 * 64 * 1024;
    pp[((size_t)0 * 64 + o) * 1024 + kl] = a0;
    pp[((size_t)1 * 64 + o) * 1024 + kl] = a1;
    pp[((size_t)2 * 64 + o) * 1024 + kl] = a2;
    pp[((size_t)3 * 64 + o) * 1024 + kl] = a3;
    pp[((size_t)4 * 64 + o) * 1024 + kl] = a4;
    pp[((size_t)5 * 64 + o) * 1024 + kl] = a5;
    pp[((size_t)6 * 64 + o) * 1024 + kl] = a6;
    pp[((size_t)7 * 64 + o) * 1024 + kl] = a7;
}

__global__ void k_om_reduce(const float* __restrict__ part, float* __restrict__ om){
    const int N = 8 * 64 * 1024;
    int e = blockIdx.x * 256 + threadIdx.x;
    if (e >= N) return;
    om[e] = part[e] + part[N + e] + part[2 * N + e];
}

// t2[b][k][w][o] = sum_l Dt[w][l] * om[b][o][k*32+l]
template<int O>
__global__ void k_inv1(const float* __restrict__ om, float* __restrict__ t2,
                       const float* __restrict__ dt){
    __shared__ float oms[32 * 65];
    int wc = blockIdx.x, k = blockIdx.y, b = blockIdx.z;
    int t = threadIdx.x;
    for (int e = t; e < 2048; e += 256){
        int o_ = e >> 5, l = e & 31;
        oms[l * 65 + o_] = om[((size_t)b * 64 + o_) * 1024 + k * 32 + l];
    }
    __syncthreads();
    int o  = t & 63;
    int wg = __builtin_amdgcn_readfirstlane(t >> 6);
    int wbase = wc * 32 + wg * 8;
    float acc[8];
    #pragma unroll
    for (int wj = 0; wj < 8; wj++) acc[wj] = 0.f;
    for (int l = 0; l < 32; l++){
        float ov = oms[l * 65 + o];
        #pragma unroll
        for (int wj = 0; wj < 8; wj++)
            acc[wj] = fmaf(dt[(wbase + wj) * KPAD + l], ov, acc[wj]);
    }
    if (o < O){
        #pragma unroll
        for (int wj = 0; wj < 8; wj++)
            t2[(((size_t)b * 32 + k) * S + wbase + wj) * 64 + o] = acc[wj];
    }
}

// CONV:  h[b][hh][w][o] = hs + gelu( conv1x1(hs)[o] + pb[o] + sum_k Dt[hh][k]*t2[b][k][w][o] )
// !CONV: h[b][hh][w][3+o] = gelu( sum_k Dt[hh][k]*t2[b][k][w][o] )   (o < 61)
// lane = o; thread covers 8 hh x 4 w pixels. h tile staged in LDS (coalesced
// float4), conv reads hs via broadcast ds_read_b128 (free), pw via lane-stride
// ds_read. Residual comes from LDS -> pure global write, no re-read.
// LDS phase-reuse: [t2s 32K | hs 32K] -> DCT -> sync -> pws overwrites t2s.
template<bool CONV>
__global__ __launch_bounds__(256, 2) void k_fused(
        const float* __restrict__ t2, float* __restrict__ h,
        const float* __restrict__ pw, const float* __restrict__ pb,
        const float* __restrict__ dt){
    __shared__ float smem[CONV ? 16384 : 8192];
    float* hs  = smem;                          // [128 px][64 i]  (CONV only)
    float* t2s = smem + (CONV ? 8192 : 0);      // [32 k * 4 w][64 o]
    float* pws = smem + 8192;                   // [64 i][65] = pw^T (CONV, after DCT)
    int ht = blockIdx.x, wt = blockIdx.y, b = blockIdx.z;
    int t = threadIdx.x;
    int o = t & 63;
    int wave = __builtin_amdgcn_readfirstlane(t >> 6);
    int w0 = wt * 4;
    int hh0 = ht * 32 + wave * 8;

    for (int e4 = t; e4 < 2048; e4 += 256){
        int k = e4 >> 6, r4 = e4 & 63;
        ((float4*)t2s)[e4] =
            *(const float4*)(t2 + ((size_t)b * 32 + k) * S * 64 + (size_t)w0 * 64 + r4 * 4);
    }
    if (CONV){
        const float* hbase = h + (((size_t)b * S + ht * 32) * S + w0) * 64;
        for (int e4 = t; e4 < 2048; e4 += 256){
            int px = e4 >> 4, i4 = e4 & 15;
            ((float4*)hs)[e4] =
                *(const float4*)(hbase + ((size_t)(px >> 2) * S + (px & 3)) * 64 + i4 * 4);
        }
    }
    __syncthreads();

    float acc[8][4];
    #pragma unroll
    for (int hj = 0; hj < 8; hj++)
        #pragma unroll
        for (int wj = 0; wj < 4; wj++) acc[hj][wj] = 0.f;

    // inverse-DCT stage 2 (reads t2s)
    for (int k = 0; k < 32; k++){
        float tv0 = t2s[(k*4+0)*64 + o];
        float tv1 = t2s[(k*4+1)*64 + o];
        float tv2 = t2s[(k*4+2)*64 + o];
        float tv3 = t2s[(k*4+3)*64 + o];
        #pragma unroll
        for (int hj = 0; hj < 8; hj++){
            float d = dt[(hh0 + hj) * KPAD + k];   // wave-uniform constant table
            acc[hj][0] = fmaf(d, tv0, acc[hj][0]);
            acc[hj][1] = fmaf(d, tv1, acc[hj][1]);
            acc[hj][2] = fmaf(d, tv2, acc[hj][2]);
            acc[hj][3] = fmaf(d, tv3, acc[hj][3]);
        }
    }

    if (CONV){
        __syncthreads();                 // all waves done with t2s
        for (int e = t; e < 4096; e += 256){
            int oo = e >> 6, i = e & 63;
            pws[i * 65 + oo] = pw[e];    // pw is 16 KB, L2-hot across blocks
        }
        __syncthreads();

        int pxb = wave * 32;
        #pragma unroll 1
        for (int i4 = 0; i4 < 16; i4++){
            float w0v = pws[(i4*4+0) * 65 + o];
            float w1v = pws[(i4*4+1) * 65 + o];
            float w2v = pws[(i4*4+2) * 65 + o];
            float w3v = pws[(i4*4+3) * 65 + o];
            #pragma unroll
            for (int hj = 0; hj < 8; hj++){
                #pragma unroll
                for (int wj = 0; wj < 4; wj++){
                    float4 hq = *(const float4*)(hs + (pxb + hj*4 + wj) * 64 + i4 * 4);
                    float a = acc[hj][wj];
                    a = fmaf(hq.x, w0v, a);
                    a = fmaf(hq.y, w1v, a);
                    a = fmaf(hq.z, w2v, a);
                    a = fmaf(hq.w, w3v, a);
                    acc[hj][wj] = a;
                }
            }
        }

        float pbv = pb[o];
        #pragma unroll
        for (int hj = 0; hj < 8; hj++){
            #pragma unroll
            for (int wj = 0; wj < 4; wj++){
                size_t pix = ((size_t)b * S + hh0 + hj) * S + w0 + wj;
                float hval = hs[(pxb + hj*4 + wj) * 64 + o];
                h[pix * 64 + o] = hval + gelu_f(acc[hj][wj] + pbv);
            }
        }
    } else {
        if (o < 61){
            #pragma unroll
            for (int hj = 0; hj < 8; hj++){
                #pragma unroll
                for (int wj = 0; wj < 4; wj++){
                    size_t pix = ((size_t)b * S + hh0 + hj) * S + w0 + wj;
                    h[pix * 64 + 3 + o] = gelu_f(acc[hj][wj]);
                }
            }
        }
    }
}

// out[px] = gelu(h_px @ fc1 + b1) @ fc2 + b2
__global__ void k_mlp(const float* __restrict__ h, const float* __restrict__ fc1w,
                      const float* __restrict__ fc1b, const float* __restrict__ fc2w,
                      const float* __restrict__ fc2b, float* __restrict__ out){
    __shared__ float hs[64 * 65];
    __shared__ float red[256];
    size_t base = (size_t)blockIdx.x * 64;   // first pixel of this block
    int t = threadIdx.x;
    const float* hrow = h + base * 64;
    for (int e = t; e < 4096; e += 256){
        int p = e >> 6, i = e & 63;
        hs[p * 65 + i] = hrow[e];
    }
    __syncthreads();
    int p = t & 63;
    int q = __builtin_amdgcn_readfirstlane(t >> 6);   // wave-uniform j-chunk
    float acc[32];
    const float* b1 = fc1b + q * 32;
    #pragma unroll
    for (int j = 0; j < 32; j++) acc[j] = b1[j];
    for (int i = 0; i < 64; i++){
        float hv = hs[p * 65 + i];
        const float* f1 = fc1w + i * 128 + q * 32;    // wave-uniform -> s_load
        #pragma unroll
        for (int j = 0; j < 32; j++) acc[j] = fmaf(hv, f1[j], acc[j]);
    }
    const float* f2 = fc2w + q * 32;
    float y = 0.f;
    #pragma unroll
    for (int j = 0; j < 32; j++) y = fmaf(gelu_f(acc[j]), f2[j], y);
    red[t] = y;
    __syncthreads();
    if (t < 64){
        out[base + t] = red[t] + red[64 + t] + red[128 + t] + red[192 + t] + fc2b[0];
    }
}

extern "C" void kernel_launch(void* const* d_in, const int* in_sizes, int n_in,
                              void* d_out, int out_size, void* d_ws, size_t ws_size,
                              hipStream_t stream) {
    const float* x    = (const float*)d_in[0];
    const float* wl   = (const float*)d_in[1];
    const float* wc[4] = {(const float*)d_in[2], (const float*)d_in[3],
                          (const float*)d_in[4], (const float*)d_in[5]};
    const float* pw[4] = {(const float*)d_in[6], (const float*)d_in[8],
                          (const float*)d_in[10], (const float*)d_in[12]};
    const float* pb[4] = {(const float*)d_in[7], (const float*)d_in[9],
                          (const float*)d_in[11], (const float*)d_in[13]};
    const float* fc1w = (const float*)d_in[14];
    const float* fc1b = (const float*)d_in[15];
    const float* fc2w = (const float*)d_in[16];
    const float* fc2b = (const float*)d_in[17];
    float* out = (float*)d_out;

    char* ws = (char*)d_ws;
    size_t off = 0;
    float* dt   = (float*)(ws + off); off += (size_t)S * KPAD * 4;              // 36,864
    float* h    = (float*)(ws + off); off += (size_t)BB * S * S * W64 * 4;      // 134,217,728
    float* tmp1 = (float*)(ws + off); off += (size_t)BB * PP * S * W64 * 4;     // 17,825,792
    float* bp   = (float*)(ws + off); off += (size_t)BB * PP * PP * W64 * 4;    // 2,367,488
    float* xp   = (float*)(ws + off); off += (size_t)576 * 1024 * 8 * 4;        // 18,874,368
    float* om   = (float*)(ws + off); off += (size_t)8 * 64 * 1024 * 4;         // 2,097,152
    float* part = (float*)(ws + off); off += (size_t)3 * 8 * 64 * 1024 * 4;     // 6,291,456
    float* t2   = (float*)(ws + off); off += (size_t)BB * 32 * S * W64 * 4;     // 16,777,216

    k_init_dt<<<36, 256, 0, stream>>>(dt);
    k_copy_x<<<(BB * S * S * CIN + 255) / 256, 256, 0, stream>>>(x, h);

    // ---- block 0: h[:, :, :, 3:] = gelu(pseudo_spectra(x, wl, 61)) ----
    k_fwd1<3><<<dim3(3, BB), 256, 0, stream>>>(x, tmp1, dt);
    k_fwd2<3><<<dim3(1, BB), 256, 0, stream>>>(tmp1, bp, dt);
    k_xp_gather<3, 3><<<dim3(32, 1), 256, 0, stream>>>(bp, xp);
    k_om<27, 61><<<768, 256, 0, stream>>>(xp, wl, part);
    k_om_reduce<<<2048, 256, 0, stream>>>(part, om);
    k_inv1<61><<<dim3(8, 32, BB), 256, 0, stream>>>(om, t2, dt);
    k_fused<false><<<dim3(8, 64, BB), 256, 0, stream>>>(t2, h, nullptr, nullptr, dt);

    // ---- blocks 1..4 ----
    for (int blk = 0; blk < 4; blk++){
        k_fwd1<64><<<dim3(64, BB), 256, 0, stream>>>(h, tmp1, dt);
        k_fwd2<64><<<dim3((PP * 64 + 255) / 256, BB), 256, 0, stream>>>(tmp1, bp, dt);
        k_xp_gather<64, 16><<<dim3(32, 4), 256, 0, stream>>>(bp, xp);
        k_om<576, 64><<<768, 256, 0, stream>>>(xp, wc[blk], part);
        k_om_reduce<<<2048, 256, 0, stream>>>(part, om);
        k_inv1<64><<<dim3(8, 32, BB), 256, 0, stream>>>(om, t2, dt);
        k_fused<true><<<dim3(8, 64, BB), 256, 0, stream>>>(t2, h, pw[blk], pb[blk], dt);
    }

    // ---- final MLP (T_fwd(T_inv2(.)) is identity for the orthonormal DCT) ----
    k_mlp<<<dim3(BB * S * S / 64), 256, 0, stream>>>(h, fc1w, fc1b, fc2w, fc2b, out);
}